// Round 1
// baseline (1116.971 us; speedup 1.0000x reference)
//
#include <hip/hip_runtime.h>
#include <math.h>

#define SEQ 2048
#define BATCH 4
#define DM 1024
#define DI 64

// ---------------------------------------------------------------------------
// Workspace layout (floats):
//   qbuf   : BATCH*SEQ*DI          =   524288   (q, layout (B,S,DI))
//   ktbuf  : BATCH*SEQ*DI          =   524288   (k transposed, layout (B,DI,S))
//   vbuf   : BATCH*SEQ*DM          =  8388608   (v, layout (B,S,DM))
//   colsum : BATCH*SEQ             =     8192
// total ~37.8 MB
// ---------------------------------------------------------------------------

// ---------- Q/K projection: one wave per (s,b) row, lane = d_internal -------
__global__ __launch_bounds__(256) void qk_proj_kernel(
    const float* __restrict__ query, const float* __restrict__ key,
    const float* __restrict__ Wq, const float* __restrict__ bq,
    const float* __restrict__ Wk, const float* __restrict__ bk,
    float* __restrict__ qbuf, float* __restrict__ ktbuf) {
  int gid  = blockIdx.x * blockDim.x + threadIdx.x;
  int wave = gid >> 6;
  int lane = threadIdx.x & 63;
  int which = wave >> 13;          // 0 => q, 1 => k  (8192 rows each)
  int r = wave & 8191;             // row in (S*B), r = s*B + b
  int s = r >> 2, b = r & 3;
  const float* x = (which ? key : query) + (size_t)r * DM;
  const float* W = which ? Wk : Wq;
  float acc = which ? bk[lane] : bq[lane];
#pragma unroll 4
  for (int d = 0; d < DM; d += 4) {
    float4 xv = *(const float4*)(x + d);
    acc = fmaf(xv.x, W[(d + 0) * DI + lane], acc);
    acc = fmaf(xv.y, W[(d + 1) * DI + lane], acc);
    acc = fmaf(xv.z, W[(d + 2) * DI + lane], acc);
    acc = fmaf(xv.w, W[(d + 3) * DI + lane], acc);
  }
  if (which == 0) qbuf[((size_t)b * SEQ + s) * DI + lane] = acc;
  else            ktbuf[((size_t)b * DI + lane) * SEQ + s] = acc;  // transposed
}

// ---------- shared fp32 GEMM core: 128x128 tile, 256 thr, 8x8 micro (4+4) ---
// C[m][n] = sum_k A[m][k] * B[k][n]; M,N multiples of 128; K multiple of 16.
__device__ __forceinline__ void gemm_core_128x128(
    const float* __restrict__ A, int lda,
    const float* __restrict__ Bm, int ldb,
    int K, float (&acc)[2][2][4][4]) {
  __shared__ float As[16][128];   // As[k][m] (A staged transposed)
  __shared__ float Bs[16][128];   // Bs[k][n]
  const int tid = threadIdx.x;
  const int ar = tid >> 1;            // 0..127  A row
  const int ak = (tid & 1) * 8;       // 0 or 8  A k-offset
  const int br = tid >> 4;            // 0..15   B k-row
  const int bn = (tid & 15) * 8;      // B n-offset
  const int tx = tid & 15;
  const int ty = tid >> 4;
  for (int k0 = 0; k0 < K; k0 += 16) {
    const float* ap = A + (size_t)ar * lda + k0 + ak;
    float4 a0 = *(const float4*)ap;
    float4 a1 = *(const float4*)(ap + 4);
    const float* bp = Bm + (size_t)(k0 + br) * ldb + bn;
    float4 b0 = *(const float4*)bp;
    float4 b1 = *(const float4*)(bp + 4);
    __syncthreads();   // previous iteration's LDS reads done before overwrite
    As[ak + 0][ar] = a0.x; As[ak + 1][ar] = a0.y;
    As[ak + 2][ar] = a0.z; As[ak + 3][ar] = a0.w;
    As[ak + 4][ar] = a1.x; As[ak + 5][ar] = a1.y;
    As[ak + 6][ar] = a1.z; As[ak + 7][ar] = a1.w;
    *(float4*)&Bs[br][bn]     = b0;
    *(float4*)&Bs[br][bn + 4] = b1;
    __syncthreads();
#pragma unroll
    for (int kk = 0; kk < 16; ++kk) {
      float4 a0v = *(const float4*)&As[kk][ty * 4];
      float4 a1v = *(const float4*)&As[kk][ty * 4 + 64];
      float4 b0v = *(const float4*)&Bs[kk][tx * 4];
      float4 b1v = *(const float4*)&Bs[kk][tx * 4 + 64];
      float am[2][4] = {{a0v.x, a0v.y, a0v.z, a0v.w},
                        {a1v.x, a1v.y, a1v.z, a1v.w}};
      float bv2[2][4] = {{b0v.x, b0v.y, b0v.z, b0v.w},
                         {b1v.x, b1v.y, b1v.z, b1v.w}};
#pragma unroll
      for (int i = 0; i < 2; ++i)
#pragma unroll
        for (int rr = 0; rr < 4; ++rr)
#pragma unroll
          for (int j = 0; j < 2; ++j)
#pragma unroll
            for (int cc = 0; cc < 4; ++cc)
              acc[i][j][rr][cc] = fmaf(am[i][rr], bv2[j][cc], acc[i][j][rr][cc]);
    }
  }
}

// ---------- V projection: value(8192x1024) @ Wv(1024x1024) + bv -> (B,S,DM) -
__global__ __launch_bounds__(256) void vproj_kernel(
    const float* __restrict__ value, const float* __restrict__ Wv,
    const float* __restrict__ bv, float* __restrict__ vbuf) {
  float acc[2][2][4][4] = {};
  int m0 = blockIdx.x * 128;
  int n0 = blockIdx.y * 128;
  gemm_core_128x128(value + (size_t)m0 * DM, DM, Wv + n0, DM, DM, acc);
  int tx = threadIdx.x & 15, ty = threadIdx.x >> 4;
#pragma unroll
  for (int i = 0; i < 2; ++i)
#pragma unroll
    for (int rr = 0; rr < 4; ++rr) {
      int r = m0 + ty * 4 + i * 64 + rr;               // r = s*B + b
      size_t crow = ((size_t)(r & 3) * SEQ + (r >> 2)) * DM;
#pragma unroll
      for (int j = 0; j < 2; ++j) {
        int n = n0 + tx * 4 + j * 64;
        float4 o;
        o.x = acc[i][j][rr][0] + bv[n + 0];
        o.y = acc[i][j][rr][1] + bv[n + 1];
        o.z = acc[i][j][rr][2] + bv[n + 2];
        o.w = acc[i][j][rr][3] + bv[n + 3];
        *(float4*)(vbuf + crow + n) = o;
      }
    }
}

// ---------- scores: q(2048x64) @ kt(64x2048) * 0.125 -> probs region --------
__global__ __launch_bounds__(256) void scores_kernel(
    const float* __restrict__ qbuf, const float* __restrict__ ktbuf,
    float* __restrict__ probs) {
  int b = blockIdx.z;
  float acc[2][2][4][4] = {};
  int m0 = blockIdx.x * 128;
  int n0 = blockIdx.y * 128;
  gemm_core_128x128(qbuf + (size_t)b * SEQ * DI + (size_t)m0 * DI, DI,
                    ktbuf + (size_t)b * DI * SEQ + n0, SEQ, DI, acc);
  float* C = probs + (size_t)b * SEQ * SEQ;
  int tx = threadIdx.x & 15, ty = threadIdx.x >> 4;
#pragma unroll
  for (int i = 0; i < 2; ++i)
#pragma unroll
    for (int rr = 0; rr < 4; ++rr) {
      int q = m0 + ty * 4 + i * 64 + rr;
#pragma unroll
      for (int j = 0; j < 2; ++j) {
        int n = n0 + tx * 4 + j * 64;
        float4 o;
        o.x = acc[i][j][rr][0] * 0.125f;
        o.y = acc[i][j][rr][1] * 0.125f;
        o.z = acc[i][j][rr][2] * 0.125f;
        o.w = acc[i][j][rr][3] * 0.125f;
        *(float4*)(C + (size_t)q * SEQ + n) = o;
      }
    }
}

// ---------- row softmax over keys (in place) --------------------------------
__global__ __launch_bounds__(256) void softmax_kernel(float* __restrict__ probs) {
  size_t row = (size_t)blockIdx.y * SEQ + blockIdx.x;    // b*SEQ + q
  float* p = probs + row * SEQ;
  int tid = threadIdx.x;
  float4 x0 = *(float4*)(p + tid * 4);
  float4 x1 = *(float4*)(p + 1024 + tid * 4);
  float m = fmaxf(fmaxf(fmaxf(x0.x, x0.y), fmaxf(x0.z, x0.w)),
                  fmaxf(fmaxf(x1.x, x1.y), fmaxf(x1.z, x1.w)));
  __shared__ float red[256];
  red[tid] = m;
  __syncthreads();
  for (int s2 = 128; s2 > 0; s2 >>= 1) {
    if (tid < s2) red[tid] = fmaxf(red[tid], red[tid + s2]);
    __syncthreads();
  }
  m = red[0];
  __syncthreads();
  x0.x = __expf(x0.x - m); x0.y = __expf(x0.y - m);
  x0.z = __expf(x0.z - m); x0.w = __expf(x0.w - m);
  x1.x = __expf(x1.x - m); x1.y = __expf(x1.y - m);
  x1.z = __expf(x1.z - m); x1.w = __expf(x1.w - m);
  float sum = x0.x + x0.y + x0.z + x0.w + x1.x + x1.y + x1.z + x1.w;
  red[tid] = sum;
  __syncthreads();
  for (int s2 = 128; s2 > 0; s2 >>= 1) {
    if (tid < s2) red[tid] += red[tid + s2];
    __syncthreads();
  }
  float inv = 1.0f / red[0];
  x0.x *= inv; x0.y *= inv; x0.z *= inv; x0.w *= inv;
  x1.x *= inv; x1.y *= inv; x1.z *= inv; x1.w *= inv;
  *(float4*)(p + tid * 4) = x0;
  *(float4*)(p + 1024 + tid * 4) = x1;
}

__global__ void zero_kernel(float* __restrict__ p, int n) {
  int i = blockIdx.x * blockDim.x + threadIdx.x;
  if (i < n) p[i] = 0.f;
}

// ---------- column sums over the query axis ---------------------------------
__global__ __launch_bounds__(256) void colsum_kernel(
    const float* __restrict__ probs, float* __restrict__ colsum) {
  int b = blockIdx.z;
  int k = blockIdx.x * 256 + threadIdx.x;
  int q0 = blockIdx.y * 128;
  const float* p = probs + (size_t)b * SEQ * SEQ + (size_t)q0 * SEQ + k;
  float sum = 0.f;
#pragma unroll 4
  for (int i = 0; i < 128; ++i) sum += p[(size_t)i * SEQ];
  atomicAdd(&colsum[b * SEQ + k], sum);
}

// ---------- renormalize probs by (1e-9 + colsum), in place ------------------
__global__ __launch_bounds__(256) void renorm_kernel(
    float* __restrict__ probs, const float* __restrict__ colsum) {
  size_t i4 = (size_t)blockIdx.x * blockDim.x + threadIdx.x;
  size_t f = i4 * 4;
  int b = (int)(f >> 22);            // SEQ*SEQ = 2^22
  int k = (int)(f & 2047);
  float4 p = *(float4*)(probs + f);
  float4 c = *(const float4*)(colsum + b * SEQ + k);
  p.x /= (1e-9f + c.x);
  p.y /= (1e-9f + c.y);
  p.z /= (1e-9f + c.z);
  p.w /= (1e-9f + c.w);
  *(float4*)(probs + f) = p;
}

// ---------- aten: probs(2048x2048) @ v(2048x1024) -> out (S,B,DM) -----------
__global__ __launch_bounds__(256) void aten_kernel(
    const float* __restrict__ probs, const float* __restrict__ vbuf,
    float* __restrict__ out) {
  int b = blockIdx.z;
  float acc[2][2][4][4] = {};
  int m0 = blockIdx.x * 128;
  int n0 = blockIdx.y * 128;
  gemm_core_128x128(probs + (size_t)b * SEQ * SEQ + (size_t)m0 * SEQ, SEQ,
                    vbuf + (size_t)b * SEQ * DM + n0, DM, SEQ, acc);
  int tx = threadIdx.x & 15, ty = threadIdx.x >> 4;
#pragma unroll
  for (int i = 0; i < 2; ++i)
#pragma unroll
    for (int rr = 0; rr < 4; ++rr) {
      int q = m0 + ty * 4 + i * 64 + rr;
      size_t crow = (size_t)q * (BATCH * DM) + (size_t)b * DM;
#pragma unroll
      for (int j = 0; j < 2; ++j) {
        int n = n0 + tx * 4 + j * 64;
        float4 o;
        o.x = acc[i][j][rr][0];
        o.y = acc[i][j][rr][1];
        o.z = acc[i][j][rr][2];
        o.w = acc[i][j][rr][3];
        *(float4*)(out + crow + n) = o;
      }
    }
}

extern "C" void kernel_launch(void* const* d_in, const int* in_sizes, int n_in,
                              void* d_out, int out_size, void* d_ws, size_t ws_size,
                              hipStream_t stream) {
  const float* query = (const float*)d_in[0];
  const float* key   = (const float*)d_in[1];
  const float* value = (const float*)d_in[2];
  const float* Wq    = (const float*)d_in[3];
  const float* bq    = (const float*)d_in[4];
  const float* Wk    = (const float*)d_in[5];
  const float* bk    = (const float*)d_in[6];
  const float* Wv    = (const float*)d_in[7];
  const float* bv    = (const float*)d_in[8];

  float* out   = (float*)d_out;
  float* aten  = out;                                   // SEQ*BATCH*DM floats
  float* probs = out + (size_t)SEQ * BATCH * DM;        // BATCH*SEQ*SEQ floats

  float* ws     = (float*)d_ws;
  float* qbuf   = ws;
  float* ktbuf  = qbuf  + (size_t)BATCH * SEQ * DI;
  float* vbuf   = ktbuf + (size_t)BATCH * SEQ * DI;
  float* colsum = vbuf  + (size_t)BATCH * SEQ * DM;

  qk_proj_kernel<<<4096, 256, 0, stream>>>(query, key, Wq, bq, Wk, bk, qbuf, ktbuf);
  vproj_kernel<<<dim3(SEQ * BATCH / 128, DM / 128), 256, 0, stream>>>(value, Wv, bv, vbuf);
  scores_kernel<<<dim3(SEQ / 128, SEQ / 128, BATCH), 256, 0, stream>>>(qbuf, ktbuf, probs);
  softmax_kernel<<<dim3(SEQ, BATCH), 256, 0, stream>>>(probs);
  zero_kernel<<<(BATCH * SEQ + 255) / 256, 256, 0, stream>>>(colsum, BATCH * SEQ);
  colsum_kernel<<<dim3(SEQ / 256, SEQ / 128, BATCH), 256, 0, stream>>>(probs, colsum);
  renorm_kernel<<<(BATCH * SEQ * SEQ / 4) / 256, 256, 0, stream>>>(probs, colsum);
  aten_kernel<<<dim3(SEQ / 128, DM / 128, BATCH), 256, 0, stream>>>(probs, vbuf, aten);
}

// Round 2
// 616.735 us; speedup vs baseline: 1.8111x; 1.8111x over previous
//
#include <hip/hip_runtime.h>
#include <math.h>

#define SEQ 2048
#define BATCH 4
#define DM 1024
#define DI 64

typedef __attribute__((ext_vector_type(8))) short bf16x8;
typedef __attribute__((ext_vector_type(4))) float f32x4;

__device__ __forceinline__ unsigned short f2bf(float f) {
  unsigned u = __float_as_uint(f);
  unsigned r = (u + 0x7fff + ((u >> 16) & 1)) >> 16;
  return (unsigned short)r;
}

__device__ __forceinline__ void gload_lds16(const void* g, void* l) {
  __builtin_amdgcn_global_load_lds(
      (const __attribute__((address_space(1))) unsigned int*)g,
      (__attribute__((address_space(3))) unsigned int*)l, 16, 0, 0);
}

// ---------------------------------------------------------------------------
// Workspace layout:
//   WvT    : 1024*1024 ushort  (Wv transposed, bf16)        2 MB
//   kbf    : B*S*DI ushort     (k projection, bf16, natural) 1 MB
//   vT     : B*DM*SEQ ushort   (v projection transposed)    16.75 MB
//   qbuf   : B*S*DI float      (q projection, fp32)          2 MB
//   colsum : B*S float                                       32 KB
// ---------------------------------------------------------------------------

// ---------- Q/K projection: one wave per (s,b) row, lane = d_internal -------
__global__ __launch_bounds__(256) void qk_proj_kernel(
    const float* __restrict__ query, const float* __restrict__ key,
    const float* __restrict__ Wq, const float* __restrict__ bq,
    const float* __restrict__ Wk, const float* __restrict__ bk,
    float* __restrict__ qbuf, unsigned short* __restrict__ kbf) {
  int gid  = blockIdx.x * blockDim.x + threadIdx.x;
  int wave = gid >> 6;
  int lane = threadIdx.x & 63;
  int which = wave >> 13;          // 0 => q, 1 => k  (8192 rows each)
  int r = wave & 8191;             // row in (S*B), r = s*B + b
  int s = r >> 2, b = r & 3;
  const float* x = (which ? key : query) + (size_t)r * DM;
  const float* W = which ? Wk : Wq;
  float acc = which ? bk[lane] : bq[lane];
#pragma unroll 4
  for (int d = 0; d < DM; d += 4) {
    float4 xv = *(const float4*)(x + d);
    acc = fmaf(xv.x, W[(d + 0) * DI + lane], acc);
    acc = fmaf(xv.y, W[(d + 1) * DI + lane], acc);
    acc = fmaf(xv.z, W[(d + 2) * DI + lane], acc);
    acc = fmaf(xv.w, W[(d + 3) * DI + lane], acc);
  }
  if (which == 0) qbuf[((size_t)b * SEQ + s) * DI + lane] = acc;
  else            kbf[((size_t)b * SEQ + s) * DI + lane] = f2bf(acc);
}

// ---------- Wv transpose + cast: WvT[n][m] = bf16(Wv[m][n]) -----------------
__global__ __launch_bounds__(256) void wvt_kernel(
    const float* __restrict__ W, unsigned short* __restrict__ WT) {
  __shared__ unsigned short t[64][65];
  int bx = blockIdx.x * 64, by = blockIdx.y * 64;   // bx: m base, by: n base
  int lx = threadIdx.x & 63, ly = threadIdx.x >> 6; // 64 x 4
#pragma unroll
  for (int i = 0; i < 64; i += 4)
    t[ly + i][lx] = f2bf(W[(size_t)(bx + ly + i) * DM + by + lx]);
  __syncthreads();
#pragma unroll
  for (int i = 0; i < 64; i += 4)
    WT[(size_t)(by + ly + i) * DM + bx + lx] = t[lx][ly + i];
}

// ---------------------------------------------------------------------------
// MFMA core: 128x128 C-tile, 256 threads = 4 waves (2x2 of 64x64),
// each wave: 4x4 of 16x16x32 bf16 MFMA. BK=32.
//   A: fp32 row-major (lda), converted to bf16 during manual LDS staging.
//   Bt: bf16 "B-transposed" row-major n x k (ldb), async global_load_lds.
// LDS: As[128][32] bf16, Bs[128][32] bf16 (rows are n).
// ---------------------------------------------------------------------------
__device__ __forceinline__ void mfma_core(
    const float* __restrict__ A, int lda,
    const unsigned short* __restrict__ Bt, int ldb,
    int K, f32x4 (&acc)[4][4],
    unsigned short* As, unsigned short* Bs) {
  const int tid  = threadIdx.x;
  const int lane = tid & 63;
  const int wave = tid >> 6;
  const int wr   = (wave >> 1) * 64;
  const int wc   = (wave & 1) * 64;
  const int lrow = lane & 15;
  const int quad = lane >> 4;

  for (int k0 = 0; k0 < K; k0 += 32) {
    __syncthreads();   // previous iteration's LDS reads complete
    // --- B tile async: 128 n-rows x 32 k bf16 = 512 x 16B chunks, 2 issues
#pragma unroll
    for (int it = 0; it < 2; ++it) {
      int c = it * 256 + wave * 64 + lane;
      int n = c >> 2, kc = (c & 3) * 8;
      gload_lds16(Bt + (size_t)n * ldb + k0 + kc,
                  Bs + (size_t)(it * 256 + wave * 64) * 8);
    }
    // --- A tile manual: 128 m-rows x 32 k, fp32 -> bf16, 4 iters of float4
#pragma unroll
    for (int it = 0; it < 4; ++it) {
      int c = it * 256 + tid;
      int m = c >> 3, kc = (c & 7) * 4;
      float4 a = *(const float4*)(A + (size_t)m * lda + k0 + kc);
      ushort4 h;
      h.x = f2bf(a.x); h.y = f2bf(a.y); h.z = f2bf(a.z); h.w = f2bf(a.w);
      *(ushort4*)&As[m * 32 + kc] = h;
    }
    __syncthreads();   // drains vmcnt (global_load_lds) + lgkm
    // --- compute
    bf16x8 af[4], bf[4];
#pragma unroll
    for (int mi = 0; mi < 4; ++mi)
      af[mi] = *(const bf16x8*)&As[(wr + mi * 16 + lrow) * 32 + quad * 8];
#pragma unroll
    for (int ni = 0; ni < 4; ++ni)
      bf[ni] = *(const bf16x8*)&Bs[(wc + ni * 16 + lrow) * 32 + quad * 8];
#pragma unroll
    for (int mi = 0; mi < 4; ++mi)
#pragma unroll
      for (int ni = 0; ni < 4; ++ni)
        acc[mi][ni] = __builtin_amdgcn_mfma_f32_16x16x32_bf16(
            af[mi], bf[ni], acc[mi][ni], 0, 0, 0);
  }
}

// ---------- V projection: value(8192x1024) @ Wv -> vT bf16 (B,DM,S) ---------
__global__ __launch_bounds__(256) void vproj_mfma(
    const float* __restrict__ value, const unsigned short* __restrict__ WvT,
    const float* __restrict__ bv, unsigned short* __restrict__ vT) {
  __shared__ __align__(16) unsigned short As[128 * 32];
  __shared__ __align__(16) unsigned short Bs[128 * 32];
  f32x4 acc[4][4] = {};
  int m0 = blockIdx.x * 128, n0 = blockIdx.y * 128;
  mfma_core(value + (size_t)m0 * DM, DM, WvT + (size_t)n0 * DM, DM, DM, acc, As, Bs);
  const int lane = threadIdx.x & 63, wave = threadIdx.x >> 6;
  const int wr = (wave >> 1) * 64, wc = (wave & 1) * 64;
  const int lrow = lane & 15, quad = lane >> 4;
#pragma unroll
  for (int mi = 0; mi < 4; ++mi) {
    int s = ((m0 + wr + mi * 16) >> 2) + quad;   // r = base + quad*4 + reg; b = reg
#pragma unroll
    for (int ni = 0; ni < 4; ++ni) {
      int n = n0 + wc + ni * 16 + lrow;
      float bias = bv[n];
#pragma unroll
      for (int reg = 0; reg < 4; ++reg)
        vT[((size_t)(reg * DM + n)) * SEQ + s] = f2bf(acc[mi][ni][reg] + bias);
    }
  }
}

// ---------- scores: q(2048x64) @ k^T * 0.125 -> probs fp32 ------------------
__global__ __launch_bounds__(256) void scores_mfma(
    const float* __restrict__ qbuf, const unsigned short* __restrict__ kbf,
    float* __restrict__ probs) {
  __shared__ __align__(16) unsigned short As[128 * 32];
  __shared__ __align__(16) unsigned short Bs[128 * 32];
  int b = blockIdx.z;
  f32x4 acc[4][4] = {};
  int m0 = blockIdx.x * 128, n0 = blockIdx.y * 128;
  mfma_core(qbuf + ((size_t)b * SEQ + m0) * DI, DI,
            kbf + ((size_t)b * SEQ + n0) * DI, DI, DI, acc, As, Bs);
  float* C = probs + (size_t)b * SEQ * SEQ;
  const int lane = threadIdx.x & 63, wave = threadIdx.x >> 6;
  const int wr = (wave >> 1) * 64, wc = (wave & 1) * 64;
  const int lrow = lane & 15, quad = lane >> 4;
#pragma unroll
  for (int mi = 0; mi < 4; ++mi) {
    int qr = m0 + wr + mi * 16 + quad * 4;
#pragma unroll
    for (int ni = 0; ni < 4; ++ni) {
      int n = n0 + wc + ni * 16 + lrow;
#pragma unroll
      for (int reg = 0; reg < 4; ++reg)
        C[(size_t)(qr + reg) * SEQ + n] = acc[mi][ni][reg] * 0.125f;
    }
  }
}

// ---------- row softmax over keys (in place) --------------------------------
__global__ __launch_bounds__(256) void softmax_kernel(float* __restrict__ probs) {
  size_t row = (size_t)blockIdx.y * SEQ + blockIdx.x;    // b*SEQ + q
  float* p = probs + row * SEQ;
  int tid = threadIdx.x;
  float4 x0 = *(float4*)(p + tid * 4);
  float4 x1 = *(float4*)(p + 1024 + tid * 4);
  float m = fmaxf(fmaxf(fmaxf(x0.x, x0.y), fmaxf(x0.z, x0.w)),
                  fmaxf(fmaxf(x1.x, x1.y), fmaxf(x1.z, x1.w)));
  __shared__ float red[256];
  red[tid] = m;
  __syncthreads();
  for (int s2 = 128; s2 > 0; s2 >>= 1) {
    if (tid < s2) red[tid] = fmaxf(red[tid], red[tid + s2]);
    __syncthreads();
  }
  m = red[0];
  __syncthreads();
  x0.x = __expf(x0.x - m); x0.y = __expf(x0.y - m);
  x0.z = __expf(x0.z - m); x0.w = __expf(x0.w - m);
  x1.x = __expf(x1.x - m); x1.y = __expf(x1.y - m);
  x1.z = __expf(x1.z - m); x1.w = __expf(x1.w - m);
  float sum = x0.x + x0.y + x0.z + x0.w + x1.x + x1.y + x1.z + x1.w;
  red[tid] = sum;
  __syncthreads();
  for (int s2 = 128; s2 > 0; s2 >>= 1) {
    if (tid < s2) red[tid] += red[tid + s2];
    __syncthreads();
  }
  float inv = 1.0f / red[0];
  x0.x *= inv; x0.y *= inv; x0.z *= inv; x0.w *= inv;
  x1.x *= inv; x1.y *= inv; x1.z *= inv; x1.w *= inv;
  *(float4*)(p + tid * 4) = x0;
  *(float4*)(p + 1024 + tid * 4) = x1;
}

__global__ void zero_kernel(float* __restrict__ p, int n) {
  int i = blockIdx.x * blockDim.x + threadIdx.x;
  if (i < n) p[i] = 0.f;
}

// ---------- column sums over the query axis ---------------------------------
__global__ __launch_bounds__(256) void colsum_kernel(
    const float* __restrict__ probs, float* __restrict__ colsum) {
  int b = blockIdx.z;
  int k = blockIdx.x * 256 + threadIdx.x;
  int q0 = blockIdx.y * 128;
  const float* p = probs + (size_t)b * SEQ * SEQ + (size_t)q0 * SEQ + k;
  float sum = 0.f;
#pragma unroll 4
  for (int i = 0; i < 128; ++i) sum += p[(size_t)i * SEQ];
  atomicAdd(&colsum[b * SEQ + k], sum);
}

// ---------- renormalize probs by (1e-9 + colsum), in place ------------------
__global__ __launch_bounds__(256) void renorm_kernel(
    float* __restrict__ probs, const float* __restrict__ colsum) {
  size_t i4 = (size_t)blockIdx.x * blockDim.x + threadIdx.x;
  size_t f = i4 * 4;
  int b = (int)(f >> 22);            // SEQ*SEQ = 2^22
  int k = (int)(f & 2047);
  float4 p = *(float4*)(probs + f);
  float4 c = *(const float4*)(colsum + b * SEQ + k);
  p.x /= (1e-9f + c.x);
  p.y /= (1e-9f + c.y);
  p.z /= (1e-9f + c.z);
  p.w /= (1e-9f + c.w);
  *(float4*)(probs + f) = p;
}

// ---------- aten: probs(2048x2048) @ v -> out (S,B,DM) ----------------------
__global__ __launch_bounds__(256) void aten_mfma(
    const float* __restrict__ probs, const unsigned short* __restrict__ vT,
    float* __restrict__ out) {
  __shared__ __align__(16) unsigned short As[128 * 32];
  __shared__ __align__(16) unsigned short Bs[128 * 32];
  int b = blockIdx.z;
  f32x4 acc[4][4] = {};
  int m0 = blockIdx.x * 128, n0 = blockIdx.y * 128;
  mfma_core(probs + (size_t)b * SEQ * SEQ + (size_t)m0 * SEQ, SEQ,
            vT + ((size_t)b * DM + n0) * SEQ, SEQ, SEQ, acc, As, Bs);
  const int lane = threadIdx.x & 63, wave = threadIdx.x >> 6;
  const int wr = (wave >> 1) * 64, wc = (wave & 1) * 64;
  const int lrow = lane & 15, quad = lane >> 4;
#pragma unroll
  for (int mi = 0; mi < 4; ++mi) {
    int qr = m0 + wr + mi * 16 + quad * 4;
#pragma unroll
    for (int ni = 0; ni < 4; ++ni) {
      int n = n0 + wc + ni * 16 + lrow;
#pragma unroll
      for (int reg = 0; reg < 4; ++reg)
        out[(size_t)(qr + reg) * (BATCH * DM) + b * DM + n] = acc[mi][ni][reg];
    }
  }
}

extern "C" void kernel_launch(void* const* d_in, const int* in_sizes, int n_in,
                              void* d_out, int out_size, void* d_ws, size_t ws_size,
                              hipStream_t stream) {
  const float* query = (const float*)d_in[0];
  const float* key   = (const float*)d_in[1];
  const float* value = (const float*)d_in[2];
  const float* Wq    = (const float*)d_in[3];
  const float* bq    = (const float*)d_in[4];
  const float* Wk    = (const float*)d_in[5];
  const float* bk    = (const float*)d_in[6];
  const float* Wv    = (const float*)d_in[7];
  const float* bv    = (const float*)d_in[8];

  float* out   = (float*)d_out;
  float* probs = out + (size_t)SEQ * BATCH * DM;        // BATCH*SEQ*SEQ floats

  unsigned short* WvT = (unsigned short*)d_ws;
  unsigned short* kbf = WvT + (size_t)DM * DM;
  unsigned short* vT  = kbf + (size_t)BATCH * SEQ * DI;
  float* qbuf   = (float*)(vT + (size_t)BATCH * DM * SEQ);
  float* colsum = qbuf + (size_t)BATCH * SEQ * DI;

  qk_proj_kernel<<<4096, 256, 0, stream>>>(query, key, Wq, bq, Wk, bk, qbuf, kbf);
  wvt_kernel<<<dim3(16, 16), 256, 0, stream>>>(Wv, WvT);
  vproj_mfma<<<dim3(SEQ * BATCH / 128, DM / 128), 256, 0, stream>>>(value, WvT, bv, vT);
  scores_mfma<<<dim3(SEQ / 128, SEQ / 128, BATCH), 256, 0, stream>>>(qbuf, kbf, probs);
  softmax_kernel<<<dim3(SEQ, BATCH), 256, 0, stream>>>(probs);
  zero_kernel<<<(BATCH * SEQ + 255) / 256, 256, 0, stream>>>(colsum, BATCH * SEQ);
  colsum_kernel<<<dim3(SEQ / 256, SEQ / 128, BATCH), 256, 0, stream>>>(probs, colsum);
  renorm_kernel<<<(BATCH * SEQ * SEQ / 4) / 256, 256, 0, stream>>>(probs, colsum);
  aten_mfma<<<dim3(SEQ / 128, DM / 128, BATCH), 256, 0, stream>>>(probs, vT, out);
}

// Round 3
// 411.736 us; speedup vs baseline: 2.7128x; 1.4979x over previous
//
#include <hip/hip_runtime.h>
#include <math.h>

#define SEQ 2048
#define BATCH 4
#define DM 1024
#define DI 64

typedef __attribute__((ext_vector_type(8))) short bf16x8;
typedef __attribute__((ext_vector_type(4))) float f32x4;

__device__ __forceinline__ unsigned short f2bf(float f) {
  unsigned u = __float_as_uint(f);
  unsigned r = (u + 0x7fff + ((u >> 16) & 1)) >> 16;
  return (unsigned short)r;
}

__device__ __forceinline__ void gload_lds16(const void* g, void* l) {
  __builtin_amdgcn_global_load_lds(
      (const __attribute__((address_space(1))) unsigned int*)g,
      (__attribute__((address_space(3))) unsigned int*)l, 16, 0, 0);
}

// ---------------------------------------------------------------------------
// Workspace layout (ushort unless noted):
//   WvT    : DM*DM        (Wv^T bf16)            2 MB
//   WqkT   : 2*DI*DM      (Wq^T, Wk^T bf16)      256 KB
//   qbf    : B*S*DI       (q proj bf16)          1 MB
//   kbf    : B*S*DI       (k proj bf16)          1 MB
//   vT     : B*DM*SEQ     (v proj^T bf16)        16.75 MB
//   colsum : B*S float                           32 KB
// ---------------------------------------------------------------------------

// ---------- Wq/Wk transpose+cast: WT[n][m] = bf16(W[m][n]), W is DMxDI ------
__global__ __launch_bounds__(256) void wqkt_kernel(
    const float* __restrict__ Wq, const float* __restrict__ Wk,
    unsigned short* __restrict__ WqkT) {
  __shared__ unsigned short t[64][65];
  const float* W = blockIdx.y ? Wk : Wq;
  unsigned short* WT = WqkT + (size_t)blockIdx.y * DI * DM;
  int bx = blockIdx.x * 64;                          // m base
  int lx = threadIdx.x & 63, ly = threadIdx.x >> 6;  // 64 x 4
#pragma unroll
  for (int i = 0; i < 64; i += 4)
    t[ly + i][lx] = f2bf(W[(size_t)(bx + ly + i) * DI + lx]);
  __syncthreads();
#pragma unroll
  for (int i = 0; i < 64; i += 4)
    WT[(size_t)(ly + i) * DM + bx + lx] = t[lx][ly + i];
}

// ---------- Wv transpose + cast: WvT[n][m] = bf16(Wv[m][n]) -----------------
__global__ __launch_bounds__(256) void wvt_kernel(
    const float* __restrict__ W, unsigned short* __restrict__ WT) {
  __shared__ unsigned short t[64][65];
  int bx = blockIdx.x * 64, by = blockIdx.y * 64;   // bx: m base, by: n base
  int lx = threadIdx.x & 63, ly = threadIdx.x >> 6; // 64 x 4
#pragma unroll
  for (int i = 0; i < 64; i += 4)
    t[ly + i][lx] = f2bf(W[(size_t)(bx + ly + i) * DM + by + lx]);
  __syncthreads();
#pragma unroll
  for (int i = 0; i < 64; i += 4)
    WT[(size_t)(by + ly + i) * DM + bx + lx] = t[lx][ly + i];
}

// ---------- Q/K projection via MFMA: 256x64 tile, 4 waves stacked -----------
// A = query|key (8192 x 1024 fp32), Bt = WqT|WkT (64 x 1024 bf16)
__global__ __launch_bounds__(256) void qkproj_mfma(
    const float* __restrict__ query, const float* __restrict__ key,
    const unsigned short* __restrict__ WqkT,
    const float* __restrict__ bq, const float* __restrict__ bk,
    unsigned short* __restrict__ qbf, unsigned short* __restrict__ kbf) {
  __shared__ __align__(16) unsigned short As[256 * 32];
  __shared__ __align__(16) unsigned short Bs[64 * 32];
  int which = blockIdx.y;
  const float* A = (which ? key : query) + (size_t)blockIdx.x * 256 * DM;
  const unsigned short* Bt = WqkT + (size_t)which * DI * DM;
  const float* bias = which ? bk : bq;
  unsigned short* outp = which ? kbf : qbf;

  const int tid = threadIdx.x;
  const int lane = tid & 63, wave = tid >> 6;
  const int lrow = lane & 15, quad = lane >> 4;
  const int wr = wave * 64;
  f32x4 acc[4][4] = {};

  for (int k0 = 0; k0 < DM; k0 += 32) {
    __syncthreads();
    // B tile: 64 n-rows x 32 k bf16 = 4KB = 256 x 16B chunks, 1 issue
    {
      int c = wave * 64 + lane;
      int n = c >> 2, kc = (c & 3) * 8;
      gload_lds16(Bt + (size_t)n * DM + k0 + kc, Bs + (size_t)(wave * 64) * 8);
    }
    // A tile: 256 rows x 32 k fp32 -> bf16, 8 float4 per thread
#pragma unroll
    for (int it = 0; it < 8; ++it) {
      int c = it * 256 + tid;
      int m = c >> 3, kc = (c & 7) * 4;
      float4 a = *(const float4*)(A + (size_t)m * DM + k0 + kc);
      ushort4 h;
      h.x = f2bf(a.x); h.y = f2bf(a.y); h.z = f2bf(a.z); h.w = f2bf(a.w);
      *(ushort4*)&As[m * 32 + kc] = h;
    }
    __syncthreads();
    bf16x8 af[4], bfr[4];
#pragma unroll
    for (int mi = 0; mi < 4; ++mi)
      af[mi] = *(const bf16x8*)&As[(wr + mi * 16 + lrow) * 32 + quad * 8];
#pragma unroll
    for (int ni = 0; ni < 4; ++ni)
      bfr[ni] = *(const bf16x8*)&Bs[(ni * 16 + lrow) * 32 + quad * 8];
#pragma unroll
    for (int mi = 0; mi < 4; ++mi)
#pragma unroll
      for (int ni = 0; ni < 4; ++ni)
        acc[mi][ni] = __builtin_amdgcn_mfma_f32_16x16x32_bf16(
            af[mi], bfr[ni], acc[mi][ni], 0, 0, 0);
  }
  // epilogue: row r = s*B + b  ->  out[(b*SEQ+s)*DI + n], bf16 with bias
#pragma unroll
  for (int mi = 0; mi < 4; ++mi) {
    int rbase = blockIdx.x * 256 + wr + mi * 16 + quad * 4;
#pragma unroll
    for (int ni = 0; ni < 4; ++ni) {
      int n = ni * 16 + lrow;
      float bb = bias[n];
#pragma unroll
      for (int reg = 0; reg < 4; ++reg) {
        int r = rbase + reg;
        int s = r >> 2, b = r & 3;
        outp[((size_t)b * SEQ + s) * DI + n] = f2bf(acc[mi][ni][reg] + bb);
      }
    }
  }
}

// ---------------------------------------------------------------------------
// MFMA core (fp32 A): 128x128 C-tile, 4 waves (2x2 of 64x64), BK=32.
// ---------------------------------------------------------------------------
__device__ __forceinline__ void mfma_core(
    const float* __restrict__ A, int lda,
    const unsigned short* __restrict__ Bt, int ldb,
    int K, f32x4 (&acc)[4][4],
    unsigned short* As, unsigned short* Bs) {
  const int tid  = threadIdx.x;
  const int lane = tid & 63;
  const int wave = tid >> 6;
  const int wr   = (wave >> 1) * 64;
  const int wc   = (wave & 1) * 64;
  const int lrow = lane & 15;
  const int quad = lane >> 4;

  for (int k0 = 0; k0 < K; k0 += 32) {
    __syncthreads();
#pragma unroll
    for (int it = 0; it < 2; ++it) {
      int c = it * 256 + wave * 64 + lane;
      int n = c >> 2, kc = (c & 3) * 8;
      gload_lds16(Bt + (size_t)n * ldb + k0 + kc,
                  Bs + (size_t)(it * 256 + wave * 64) * 8);
    }
#pragma unroll
    for (int it = 0; it < 4; ++it) {
      int c = it * 256 + tid;
      int m = c >> 3, kc = (c & 7) * 4;
      float4 a = *(const float4*)(A + (size_t)m * lda + k0 + kc);
      ushort4 h;
      h.x = f2bf(a.x); h.y = f2bf(a.y); h.z = f2bf(a.z); h.w = f2bf(a.w);
      *(ushort4*)&As[m * 32 + kc] = h;
    }
    __syncthreads();
    bf16x8 af[4], bfr[4];
#pragma unroll
    for (int mi = 0; mi < 4; ++mi)
      af[mi] = *(const bf16x8*)&As[(wr + mi * 16 + lrow) * 32 + quad * 8];
#pragma unroll
    for (int ni = 0; ni < 4; ++ni)
      bfr[ni] = *(const bf16x8*)&Bs[(wc + ni * 16 + lrow) * 32 + quad * 8];
#pragma unroll
    for (int mi = 0; mi < 4; ++mi)
#pragma unroll
      for (int ni = 0; ni < 4; ++ni)
        acc[mi][ni] = __builtin_amdgcn_mfma_f32_16x16x32_bf16(
            af[mi], bfr[ni], acc[mi][ni], 0, 0, 0);
  }
}

// ---------- V projection: value(8192x1024) @ Wv -> vT bf16 (B,DM,S) ---------
__global__ __launch_bounds__(256) void vproj_mfma(
    const float* __restrict__ value, const unsigned short* __restrict__ WvT,
    const float* __restrict__ bv, unsigned short* __restrict__ vT) {
  __shared__ __align__(16) unsigned short As[128 * 32];
  __shared__ __align__(16) unsigned short Bs[128 * 32];
  f32x4 acc[4][4] = {};
  int m0 = blockIdx.x * 128, n0 = blockIdx.y * 128;
  mfma_core(value + (size_t)m0 * DM, DM, WvT + (size_t)n0 * DM, DM, DM, acc, As, Bs);
  const int lane = threadIdx.x & 63, wave = threadIdx.x >> 6;
  const int wr = (wave >> 1) * 64, wc = (wave & 1) * 64;
  const int lrow = lane & 15, quad = lane >> 4;
#pragma unroll
  for (int mi = 0; mi < 4; ++mi) {
    int s = ((m0 + wr + mi * 16) >> 2) + quad;   // r = base + quad*4 + reg; b = reg
#pragma unroll
    for (int ni = 0; ni < 4; ++ni) {
      int n = n0 + wc + ni * 16 + lrow;
      float bias = bv[n];
#pragma unroll
      for (int reg = 0; reg < 4; ++reg)
        vT[((size_t)(reg * DM + n)) * SEQ + s] = f2bf(acc[mi][ni][reg] + bias);
    }
  }
}

// ---------- scores: q @ k^T * 0.125 -> probs fp32 (both operands bf16) ------
__global__ __launch_bounds__(256) void scores_mfma(
    const unsigned short* __restrict__ qbf, const unsigned short* __restrict__ kbf,
    float* __restrict__ probs) {
  __shared__ __align__(16) unsigned short As[128 * 32];
  __shared__ __align__(16) unsigned short Bs[128 * 32];
  int b = blockIdx.z;
  const unsigned short* Aq = qbf + ((size_t)b * SEQ + blockIdx.x * 128) * DI;
  const unsigned short* Bk = kbf + ((size_t)b * SEQ + blockIdx.y * 128) * DI;
  const int tid = threadIdx.x;
  const int lane = tid & 63, wave = tid >> 6;
  const int lrow = lane & 15, quad = lane >> 4;
  const int wr = (wave >> 1) * 64, wc = (wave & 1) * 64;
  f32x4 acc[4][4] = {};
  for (int k0 = 0; k0 < DI; k0 += 32) {
    __syncthreads();
#pragma unroll
    for (int it = 0; it < 2; ++it) {
      int c = it * 256 + wave * 64 + lane;
      int m = c >> 2, kc = (c & 3) * 8;
      gload_lds16(Aq + (size_t)m * DI + k0 + kc,
                  As + (size_t)(it * 256 + wave * 64) * 8);
    }
#pragma unroll
    for (int it = 0; it < 2; ++it) {
      int c = it * 256 + wave * 64 + lane;
      int n = c >> 2, kc = (c & 3) * 8;
      gload_lds16(Bk + (size_t)n * DI + k0 + kc,
                  Bs + (size_t)(it * 256 + wave * 64) * 8);
    }
    __syncthreads();
    bf16x8 af[4], bfr[4];
#pragma unroll
    for (int mi = 0; mi < 4; ++mi)
      af[mi] = *(const bf16x8*)&As[(wr + mi * 16 + lrow) * 32 + quad * 8];
#pragma unroll
    for (int ni = 0; ni < 4; ++ni)
      bfr[ni] = *(const bf16x8*)&Bs[(wc + ni * 16 + lrow) * 32 + quad * 8];
#pragma unroll
    for (int mi = 0; mi < 4; ++mi)
#pragma unroll
      for (int ni = 0; ni < 4; ++ni)
        acc[mi][ni] = __builtin_amdgcn_mfma_f32_16x16x32_bf16(
            af[mi], bfr[ni], acc[mi][ni], 0, 0, 0);
  }
  float* C = probs + (size_t)b * SEQ * SEQ;
#pragma unroll
  for (int mi = 0; mi < 4; ++mi) {
    int qr = blockIdx.x * 128 + wr + mi * 16 + quad * 4;
#pragma unroll
    for (int ni = 0; ni < 4; ++ni) {
      int n = blockIdx.y * 128 + wc + ni * 16 + lrow;
#pragma unroll
      for (int reg = 0; reg < 4; ++reg)
        C[(size_t)(qr + reg) * SEQ + n] = acc[mi][ni][reg] * 0.125f;
    }
  }
}

// ---------- row softmax over keys (in place) --------------------------------
__global__ __launch_bounds__(256) void softmax_kernel(float* __restrict__ probs) {
  size_t row = (size_t)blockIdx.y * SEQ + blockIdx.x;    // b*SEQ + q
  float* p = probs + row * SEQ;
  int tid = threadIdx.x;
  float4 x0 = *(float4*)(p + tid * 4);
  float4 x1 = *(float4*)(p + 1024 + tid * 4);
  float m = fmaxf(fmaxf(fmaxf(x0.x, x0.y), fmaxf(x0.z, x0.w)),
                  fmaxf(fmaxf(x1.x, x1.y), fmaxf(x1.z, x1.w)));
  __shared__ float red[256];
  red[tid] = m;
  __syncthreads();
  for (int s2 = 128; s2 > 0; s2 >>= 1) {
    if (tid < s2) red[tid] = fmaxf(red[tid], red[tid + s2]);
    __syncthreads();
  }
  m = red[0];
  __syncthreads();
  x0.x = __expf(x0.x - m); x0.y = __expf(x0.y - m);
  x0.z = __expf(x0.z - m); x0.w = __expf(x0.w - m);
  x1.x = __expf(x1.x - m); x1.y = __expf(x1.y - m);
  x1.z = __expf(x1.z - m); x1.w = __expf(x1.w - m);
  float sum = x0.x + x0.y + x0.z + x0.w + x1.x + x1.y + x1.z + x1.w;
  red[tid] = sum;
  __syncthreads();
  for (int s2 = 128; s2 > 0; s2 >>= 1) {
    if (tid < s2) red[tid] += red[tid + s2];
    __syncthreads();
  }
  float inv = 1.0f / red[0];
  x0.x *= inv; x0.y *= inv; x0.z *= inv; x0.w *= inv;
  x1.x *= inv; x1.y *= inv; x1.z *= inv; x1.w *= inv;
  *(float4*)(p + tid * 4) = x0;
  *(float4*)(p + 1024 + tid * 4) = x1;
}

__global__ void zero_kernel(float* __restrict__ p, int n) {
  int i = blockIdx.x * blockDim.x + threadIdx.x;
  if (i < n) p[i] = 0.f;
}

// ---------- column sums over the query axis ---------------------------------
__global__ __launch_bounds__(256) void colsum_kernel(
    const float* __restrict__ probs, float* __restrict__ colsum) {
  int b = blockIdx.z;
  int k = blockIdx.x * 256 + threadIdx.x;
  int q0 = blockIdx.y * 128;
  const float* p = probs + (size_t)b * SEQ * SEQ + (size_t)q0 * SEQ + k;
  float sum = 0.f;
#pragma unroll 4
  for (int i = 0; i < 128; ++i) sum += p[(size_t)i * SEQ];
  atomicAdd(&colsum[b * SEQ + k], sum);
}

// ---------- renormalize probs by (1e-9 + colsum), in place ------------------
__global__ __launch_bounds__(256) void renorm_kernel(
    float* __restrict__ probs, const float* __restrict__ colsum) {
  size_t i4 = (size_t)blockIdx.x * blockDim.x + threadIdx.x;
  size_t f = i4 * 4;
  int b = (int)(f >> 22);            // SEQ*SEQ = 2^22
  int k = (int)(f & 2047);
  float4 p = *(float4*)(probs + f);
  float4 c = *(const float4*)(colsum + b * SEQ + k);
  p.x /= (1e-9f + c.x);
  p.y /= (1e-9f + c.y);
  p.z /= (1e-9f + c.z);
  p.w /= (1e-9f + c.w);
  *(float4*)(probs + f) = p;
}

// ---------- aten: probs(2048x2048) @ v -> out (S,B,DM) ----------------------
__global__ __launch_bounds__(256) void aten_mfma(
    const float* __restrict__ probs, const unsigned short* __restrict__ vT,
    float* __restrict__ out) {
  __shared__ __align__(16) unsigned short As[128 * 32];
  __shared__ __align__(16) unsigned short Bs[128 * 32];
  int b = blockIdx.z;
  f32x4 acc[4][4] = {};
  int m0 = blockIdx.x * 128, n0 = blockIdx.y * 128;
  mfma_core(probs + (size_t)b * SEQ * SEQ + (size_t)m0 * SEQ, SEQ,
            vT + ((size_t)b * DM + n0) * SEQ, SEQ, SEQ, acc, As, Bs);
  const int lane = threadIdx.x & 63, wave = threadIdx.x >> 6;
  const int wr = (wave >> 1) * 64, wc = (wave & 1) * 64;
  const int lrow = lane & 15, quad = lane >> 4;
#pragma unroll
  for (int mi = 0; mi < 4; ++mi) {
    int qr = m0 + wr + mi * 16 + quad * 4;
#pragma unroll
    for (int ni = 0; ni < 4; ++ni) {
      int n = n0 + wc + ni * 16 + lrow;
#pragma unroll
      for (int reg = 0; reg < 4; ++reg)
        out[(size_t)(qr + reg) * (BATCH * DM) + b * DM + n] = acc[mi][ni][reg];
    }
  }
}

extern "C" void kernel_launch(void* const* d_in, const int* in_sizes, int n_in,
                              void* d_out, int out_size, void* d_ws, size_t ws_size,
                              hipStream_t stream) {
  const float* query = (const float*)d_in[0];
  const float* key   = (const float*)d_in[1];
  const float* value = (const float*)d_in[2];
  const float* Wq    = (const float*)d_in[3];
  const float* bq    = (const float*)d_in[4];
  const float* Wk    = (const float*)d_in[5];
  const float* bk    = (const float*)d_in[6];
  const float* Wv    = (const float*)d_in[7];
  const float* bv    = (const float*)d_in[8];

  float* out   = (float*)d_out;
  float* probs = out + (size_t)SEQ * BATCH * DM;        // BATCH*SEQ*SEQ floats

  unsigned short* WvT  = (unsigned short*)d_ws;
  unsigned short* WqkT = WvT  + (size_t)DM * DM;
  unsigned short* qbf  = WqkT + (size_t)2 * DI * DM;
  unsigned short* kbf  = qbf  + (size_t)BATCH * SEQ * DI;
  unsigned short* vT   = kbf  + (size_t)BATCH * SEQ * DI;
  float* colsum = (float*)(vT + (size_t)BATCH * DM * SEQ);

  wqkt_kernel<<<dim3(16, 2), 256, 0, stream>>>(Wq, Wk, WqkT);
  qkproj_mfma<<<dim3(SEQ * BATCH / 256, 2), 256, 0, stream>>>(
      query, key, WqkT, bq, bk, qbf, kbf);
  wvt_kernel<<<dim3(16, 16), 256, 0, stream>>>(Wv, WvT);
  vproj_mfma<<<dim3(SEQ * BATCH / 128, DM / 128), 256, 0, stream>>>(value, WvT, bv, vT);
  scores_mfma<<<dim3(SEQ / 128, SEQ / 128, BATCH), 256, 0, stream>>>(qbf, kbf, probs);
  softmax_kernel<<<dim3(SEQ, BATCH), 256, 0, stream>>>(probs);
  zero_kernel<<<(BATCH * SEQ + 255) / 256, 256, 0, stream>>>(colsum, BATCH * SEQ);
  colsum_kernel<<<dim3(SEQ / 256, SEQ / 128, BATCH), 256, 0, stream>>>(probs, colsum);
  renorm_kernel<<<(BATCH * SEQ * SEQ / 4) / 256, 256, 0, stream>>>(probs, colsum);
  aten_mfma<<<dim3(SEQ / 128, DM / 128, BATCH), 256, 0, stream>>>(probs, vT, out);
}

// Round 4
// 398.779 us; speedup vs baseline: 2.8010x; 1.0325x over previous
//
#include <hip/hip_runtime.h>
#include <math.h>

#define SEQ 2048
#define BATCH 4
#define DM 1024
#define DI 64

typedef __attribute__((ext_vector_type(8))) short bf16x8;
typedef __attribute__((ext_vector_type(4))) float f32x4;

__device__ __forceinline__ unsigned short f2bf(float f) {
  unsigned u = __float_as_uint(f);
  unsigned r = (u + 0x7fff + ((u >> 16) & 1)) >> 16;
  return (unsigned short)r;
}

__device__ __forceinline__ void gload_lds16(const void* g, void* l) {
  __builtin_amdgcn_global_load_lds(
      (const __attribute__((address_space(1))) unsigned int*)g,
      (__attribute__((address_space(3))) unsigned int*)l, 16, 0, 0);
}

// ---------------------------------------------------------------------------
// Workspace layout (ushort unless noted):
//   WvT    : DM*DM        (Wv^T bf16)            2 MB
//   WqkT   : 2*DI*DM      (Wq^T, Wk^T bf16)      256 KB
//   qbf    : B*S*DI       (q proj bf16)          1 MB
//   kbf    : B*S*DI       (k proj bf16)          1 MB
//   vT     : B*DM*SEQ     (v proj^T bf16)        16.75 MB
//   smb    : B*S*S        (renormed probs bf16)  33.55 MB
//   colsum : B*S float                           32 KB
//   invcol : B*S float                           32 KB
// total ~54.6 MB
// ---------------------------------------------------------------------------

// ---------- Wq/Wk transpose+cast: WT[n][m] = bf16(W[m][n]), W is DMxDI ------
__global__ __launch_bounds__(256) void wqkt_kernel(
    const float* __restrict__ Wq, const float* __restrict__ Wk,
    unsigned short* __restrict__ WqkT) {
  __shared__ unsigned short t[64][65];
  const float* W = blockIdx.y ? Wk : Wq;
  unsigned short* WT = WqkT + (size_t)blockIdx.y * DI * DM;
  int bx = blockIdx.x * 64;                          // m base
  int lx = threadIdx.x & 63, ly = threadIdx.x >> 6;  // 64 x 4
#pragma unroll
  for (int i = 0; i < 64; i += 4)
    t[ly + i][lx] = f2bf(W[(size_t)(bx + ly + i) * DI + lx]);
  __syncthreads();
#pragma unroll
  for (int i = 0; i < 64; i += 4)
    WT[(size_t)(ly + i) * DM + bx + lx] = t[lx][ly + i];
}

// ---------- Wv transpose + cast: WvT[n][m] = bf16(Wv[m][n]) -----------------
__global__ __launch_bounds__(256) void wvt_kernel(
    const float* __restrict__ W, unsigned short* __restrict__ WT) {
  __shared__ unsigned short t[64][65];
  int bx = blockIdx.x * 64, by = blockIdx.y * 64;   // bx: m base, by: n base
  int lx = threadIdx.x & 63, ly = threadIdx.x >> 6; // 64 x 4
#pragma unroll
  for (int i = 0; i < 64; i += 4)
    t[ly + i][lx] = f2bf(W[(size_t)(bx + ly + i) * DM + by + lx]);
  __syncthreads();
#pragma unroll
  for (int i = 0; i < 64; i += 4)
    WT[(size_t)(by + ly + i) * DM + bx + lx] = t[lx][ly + i];
}

// ---------- Q/K projection via MFMA: 256x64 tile, 4 waves stacked -----------
__global__ __launch_bounds__(256) void qkproj_mfma(
    const float* __restrict__ query, const float* __restrict__ key,
    const unsigned short* __restrict__ WqkT,
    const float* __restrict__ bq, const float* __restrict__ bk,
    unsigned short* __restrict__ qbf, unsigned short* __restrict__ kbf) {
  __shared__ __align__(16) unsigned short As[256 * 32];
  __shared__ __align__(16) unsigned short Bs[64 * 32];
  int which = blockIdx.y;
  const float* A = (which ? key : query) + (size_t)blockIdx.x * 256 * DM;
  const unsigned short* Bt = WqkT + (size_t)which * DI * DM;
  const float* bias = which ? bk : bq;
  unsigned short* outp = which ? kbf : qbf;

  const int tid = threadIdx.x;
  const int lane = tid & 63, wave = tid >> 6;
  const int lrow = lane & 15, quad = lane >> 4;
  const int wr = wave * 64;
  f32x4 acc[4][4] = {};

  for (int k0 = 0; k0 < DM; k0 += 32) {
    __syncthreads();
    {
      int c = wave * 64 + lane;
      int n = c >> 2, kc = (c & 3) * 8;
      gload_lds16(Bt + (size_t)n * DM + k0 + kc, Bs + (size_t)(wave * 64) * 8);
    }
#pragma unroll
    for (int it = 0; it < 8; ++it) {
      int c = it * 256 + tid;
      int m = c >> 3, kc = (c & 7) * 4;
      float4 a = *(const float4*)(A + (size_t)m * DM + k0 + kc);
      ushort4 h;
      h.x = f2bf(a.x); h.y = f2bf(a.y); h.z = f2bf(a.z); h.w = f2bf(a.w);
      *(ushort4*)&As[m * 32 + kc] = h;
    }
    __syncthreads();
    bf16x8 af[4], bfr[4];
#pragma unroll
    for (int mi = 0; mi < 4; ++mi)
      af[mi] = *(const bf16x8*)&As[(wr + mi * 16 + lrow) * 32 + quad * 8];
#pragma unroll
    for (int ni = 0; ni < 4; ++ni)
      bfr[ni] = *(const bf16x8*)&Bs[(ni * 16 + lrow) * 32 + quad * 8];
#pragma unroll
    for (int mi = 0; mi < 4; ++mi)
#pragma unroll
      for (int ni = 0; ni < 4; ++ni)
        acc[mi][ni] = __builtin_amdgcn_mfma_f32_16x16x32_bf16(
            af[mi], bfr[ni], acc[mi][ni], 0, 0, 0);
  }
#pragma unroll
  for (int mi = 0; mi < 4; ++mi) {
    int rbase = blockIdx.x * 256 + wr + mi * 16 + quad * 4;
#pragma unroll
    for (int ni = 0; ni < 4; ++ni) {
      int n = ni * 16 + lrow;
      float bb = bias[n];
#pragma unroll
      for (int reg = 0; reg < 4; ++reg) {
        int r = rbase + reg;
        int s = r >> 2, b = r & 3;
        outp[((size_t)b * SEQ + s) * DI + n] = f2bf(acc[mi][ni][reg] + bb);
      }
    }
  }
}

// ---------------------------------------------------------------------------
// MFMA core, fp32 A (manual convert) + async bf16 B. 128x128, BK=32.
// ---------------------------------------------------------------------------
__device__ __forceinline__ void mfma_core_fa(
    const float* __restrict__ A, int lda,
    const unsigned short* __restrict__ Bt, int ldb,
    int K, f32x4 (&acc)[4][4],
    unsigned short* As, unsigned short* Bs) {
  const int tid  = threadIdx.x;
  const int lane = tid & 63;
  const int wave = tid >> 6;
  const int wr   = (wave >> 1) * 64;
  const int wc   = (wave & 1) * 64;
  const int lrow = lane & 15;
  const int quad = lane >> 4;

  for (int k0 = 0; k0 < K; k0 += 32) {
    __syncthreads();
#pragma unroll
    for (int it = 0; it < 2; ++it) {
      int c = it * 256 + wave * 64 + lane;
      int n = c >> 2, kc = (c & 3) * 8;
      gload_lds16(Bt + (size_t)n * ldb + k0 + kc,
                  Bs + (size_t)(it * 256 + wave * 64) * 8);
    }
#pragma unroll
    for (int it = 0; it < 4; ++it) {
      int c = it * 256 + tid;
      int m = c >> 3, kc = (c & 7) * 4;
      float4 a = *(const float4*)(A + (size_t)m * lda + k0 + kc);
      ushort4 h;
      h.x = f2bf(a.x); h.y = f2bf(a.y); h.z = f2bf(a.z); h.w = f2bf(a.w);
      *(ushort4*)&As[m * 32 + kc] = h;
    }
    __syncthreads();
    bf16x8 af[4], bfr[4];
#pragma unroll
    for (int mi = 0; mi < 4; ++mi)
      af[mi] = *(const bf16x8*)&As[(wr + mi * 16 + lrow) * 32 + quad * 8];
#pragma unroll
    for (int ni = 0; ni < 4; ++ni)
      bfr[ni] = *(const bf16x8*)&Bs[(wc + ni * 16 + lrow) * 32 + quad * 8];
#pragma unroll
    for (int mi = 0; mi < 4; ++mi)
#pragma unroll
      for (int ni = 0; ni < 4; ++ni)
        acc[mi][ni] = __builtin_amdgcn_mfma_f32_16x16x32_bf16(
            af[mi], bfr[ni], acc[mi][ni], 0, 0, 0);
  }
}

// ---------------------------------------------------------------------------
// MFMA core, both operands bf16, dual async staging, XOR bank swizzle.
// LDS chunk (row, c) stored at slot c ^ ((row>>1)&3)  -> 2-way banks (free).
// ---------------------------------------------------------------------------
__device__ __forceinline__ void mfma_core_bb(
    const unsigned short* __restrict__ At, int lda,
    const unsigned short* __restrict__ Bt, int ldb,
    int K, f32x4 (&acc)[4][4],
    unsigned short* As, unsigned short* Bs) {
  const int tid  = threadIdx.x;
  const int lane = tid & 63;
  const int wave = tid >> 6;
  const int wr   = (wave >> 1) * 64;
  const int wc   = (wave & 1) * 64;
  const int lrow = lane & 15;
  const int quad = lane >> 4;
  const int sw   = (quad ^ ((lrow >> 1) & 3)) * 8;   // swizzled chunk offset

  for (int k0 = 0; k0 < K; k0 += 32) {
    __syncthreads();
#pragma unroll
    for (int it = 0; it < 2; ++it) {
      int c = it * 256 + wave * 64 + lane;
      int m = c >> 2, kc = ((c & 3) ^ ((c >> 3) & 3)) * 8;
      gload_lds16(At + (size_t)m * lda + k0 + kc,
                  As + (size_t)(it * 256 + wave * 64) * 8);
    }
#pragma unroll
    for (int it = 0; it < 2; ++it) {
      int c = it * 256 + wave * 64 + lane;
      int n = c >> 2, kc = ((c & 3) ^ ((c >> 3) & 3)) * 8;
      gload_lds16(Bt + (size_t)n * ldb + k0 + kc,
                  Bs + (size_t)(it * 256 + wave * 64) * 8);
    }
    __syncthreads();
    bf16x8 af[4], bfr[4];
#pragma unroll
    for (int mi = 0; mi < 4; ++mi)
      af[mi] = *(const bf16x8*)&As[(wr + mi * 16 + lrow) * 32 + sw];
#pragma unroll
    for (int ni = 0; ni < 4; ++ni)
      bfr[ni] = *(const bf16x8*)&Bs[(wc + ni * 16 + lrow) * 32 + sw];
#pragma unroll
    for (int mi = 0; mi < 4; ++mi)
#pragma unroll
      for (int ni = 0; ni < 4; ++ni)
        acc[mi][ni] = __builtin_amdgcn_mfma_f32_16x16x32_bf16(
            af[mi], bfr[ni], acc[mi][ni], 0, 0, 0);
  }
}

// ---------- V projection: value(8192x1024) @ Wv -> vT bf16 (B,DM,S) ---------
__global__ __launch_bounds__(256) void vproj_mfma(
    const float* __restrict__ value, const unsigned short* __restrict__ WvT,
    const float* __restrict__ bv, unsigned short* __restrict__ vT) {
  __shared__ __align__(16) unsigned short As[128 * 32];
  __shared__ __align__(16) unsigned short Bs[128 * 32];
  f32x4 acc[4][4] = {};
  int m0 = blockIdx.x * 128, n0 = blockIdx.y * 128;
  mfma_core_fa(value + (size_t)m0 * DM, DM, WvT + (size_t)n0 * DM, DM, DM, acc, As, Bs);
  const int lane = threadIdx.x & 63, wave = threadIdx.x >> 6;
  const int wr = (wave >> 1) * 64, wc = (wave & 1) * 64;
  const int lrow = lane & 15, quad = lane >> 4;
#pragma unroll
  for (int mi = 0; mi < 4; ++mi) {
    int s = ((m0 + wr + mi * 16) >> 2) + quad;   // b = reg, s = key position
#pragma unroll
    for (int ni = 0; ni < 4; ++ni) {
      int n = n0 + wc + ni * 16 + lrow;
      float bias = bv[n];
#pragma unroll
      for (int reg = 0; reg < 4; ++reg)
        vT[((size_t)(reg * DM + n)) * SEQ + s] = f2bf(acc[mi][ni][reg] + bias);
    }
  }
}

// ---------- scores: q @ k^T * 0.125 -> probs fp32 ---------------------------
__global__ __launch_bounds__(256) void scores_mfma(
    const unsigned short* __restrict__ qbf, const unsigned short* __restrict__ kbf,
    float* __restrict__ probs) {
  __shared__ __align__(16) unsigned short As[128 * 32];
  __shared__ __align__(16) unsigned short Bs[128 * 32];
  int b = blockIdx.z;
  f32x4 acc[4][4] = {};
  mfma_core_bb(qbf + ((size_t)b * SEQ + blockIdx.x * 128) * DI, DI,
               kbf + ((size_t)b * SEQ + blockIdx.y * 128) * DI, DI, DI,
               acc, As, Bs);
  float* C = probs + (size_t)b * SEQ * SEQ;
  const int lane = threadIdx.x & 63, wave = threadIdx.x >> 6;
  const int wr = (wave >> 1) * 64, wc = (wave & 1) * 64;
  const int lrow = lane & 15, quad = lane >> 4;
#pragma unroll
  for (int mi = 0; mi < 4; ++mi) {
    int qr = blockIdx.x * 128 + wr + mi * 16 + quad * 4;
#pragma unroll
    for (int ni = 0; ni < 4; ++ni) {
      int n = blockIdx.y * 128 + wc + ni * 16 + lrow;
#pragma unroll
      for (int reg = 0; reg < 4; ++reg)
        C[(size_t)(qr + reg) * SEQ + n] = acc[mi][ni][reg] * 0.125f;
    }
  }
}

// ---------- row softmax over keys (in place) --------------------------------
__global__ __launch_bounds__(256) void softmax_kernel(float* __restrict__ probs) {
  size_t row = (size_t)blockIdx.y * SEQ + blockIdx.x;    // b*SEQ + q
  float* p = probs + row * SEQ;
  int tid = threadIdx.x;
  float4 x0 = *(float4*)(p + tid * 4);
  float4 x1 = *(float4*)(p + 1024 + tid * 4);
  float m = fmaxf(fmaxf(fmaxf(x0.x, x0.y), fmaxf(x0.z, x0.w)),
                  fmaxf(fmaxf(x1.x, x1.y), fmaxf(x1.z, x1.w)));
  __shared__ float red[256];
  red[tid] = m;
  __syncthreads();
  for (int s2 = 128; s2 > 0; s2 >>= 1) {
    if (tid < s2) red[tid] = fmaxf(red[tid], red[tid + s2]);
    __syncthreads();
  }
  m = red[0];
  __syncthreads();
  x0.x = __expf(x0.x - m); x0.y = __expf(x0.y - m);
  x0.z = __expf(x0.z - m); x0.w = __expf(x0.w - m);
  x1.x = __expf(x1.x - m); x1.y = __expf(x1.y - m);
  x1.z = __expf(x1.z - m); x1.w = __expf(x1.w - m);
  float sum = x0.x + x0.y + x0.z + x0.w + x1.x + x1.y + x1.z + x1.w;
  red[tid] = sum;
  __syncthreads();
  for (int s2 = 128; s2 > 0; s2 >>= 1) {
    if (tid < s2) red[tid] += red[tid + s2];
    __syncthreads();
  }
  float inv = 1.0f / red[0];
  x0.x *= inv; x0.y *= inv; x0.z *= inv; x0.w *= inv;
  x1.x *= inv; x1.y *= inv; x1.z *= inv; x1.w *= inv;
  *(float4*)(p + tid * 4) = x0;
  *(float4*)(p + 1024 + tid * 4) = x1;
}

__global__ void zero_kernel(float* __restrict__ p, int n) {
  int i = blockIdx.x * blockDim.x + threadIdx.x;
  if (i < n) p[i] = 0.f;
}

// ---------- column sums over the query axis ---------------------------------
__global__ __launch_bounds__(256) void colsum_kernel(
    const float* __restrict__ probs, float* __restrict__ colsum) {
  int b = blockIdx.z;
  int k = blockIdx.x * 256 + threadIdx.x;
  int q0 = blockIdx.y * 128;
  const float* p = probs + (size_t)b * SEQ * SEQ + (size_t)q0 * SEQ + k;
  float sum = 0.f;
#pragma unroll 4
  for (int i = 0; i < 128; ++i) sum += p[(size_t)i * SEQ];
  atomicAdd(&colsum[b * SEQ + k], sum);
}

__global__ void invcol_kernel(const float* __restrict__ colsum,
                              float* __restrict__ invcol, int n) {
  int i = blockIdx.x * blockDim.x + threadIdx.x;
  if (i < n) invcol[i] = 1.0f / (1e-9f + colsum[i]);
}

// ---------- renorm: probs *= invcol (in place) + bf16 copy to smb -----------
__global__ __launch_bounds__(256) void renorm_kernel(
    float* __restrict__ probs, const float* __restrict__ invcol,
    unsigned short* __restrict__ smb) {
  size_t i4 = (size_t)blockIdx.x * blockDim.x + threadIdx.x;
  size_t f = i4 * 4;
  int b = (int)(f >> 22);            // SEQ*SEQ = 2^22
  int k = (int)(f & 2047);
  float4 p = *(float4*)(probs + f);
  float4 c = *(const float4*)(invcol + b * SEQ + k);
  p.x *= c.x; p.y *= c.y; p.z *= c.z; p.w *= c.w;
  *(float4*)(probs + f) = p;
  ushort4 h;
  h.x = f2bf(p.x); h.y = f2bf(p.y); h.z = f2bf(p.z); h.w = f2bf(p.w);
  *(ushort4*)(smb + f) = h;
}

// ---------- aten: smb(bf16) @ vT(bf16) -> out (S,B,DM) ----------------------
__global__ __launch_bounds__(256) void aten_mfma(
    const unsigned short* __restrict__ smb, const unsigned short* __restrict__ vT,
    float* __restrict__ out) {
  __shared__ __align__(16) unsigned short As[128 * 32];
  __shared__ __align__(16) unsigned short Bs[128 * 32];
  int b = blockIdx.z;
  f32x4 acc[4][4] = {};
  int m0 = blockIdx.x * 128, n0 = blockIdx.y * 128;
  mfma_core_bb(smb + ((size_t)b * SEQ + m0) * SEQ, SEQ,
               vT + ((size_t)b * DM + n0) * SEQ, SEQ, SEQ, acc, As, Bs);
  const int lane = threadIdx.x & 63, wave = threadIdx.x >> 6;
  const int wr = (wave >> 1) * 64, wc = (wave & 1) * 64;
  const int lrow = lane & 15, quad = lane >> 4;
#pragma unroll
  for (int mi = 0; mi < 4; ++mi) {
    int qr = m0 + wr + mi * 16 + quad * 4;
#pragma unroll
    for (int ni = 0; ni < 4; ++ni) {
      int n = n0 + wc + ni * 16 + lrow;
#pragma unroll
      for (int reg = 0; reg < 4; ++reg)
        out[(size_t)(qr + reg) * (BATCH * DM) + b * DM + n] = acc[mi][ni][reg];
    }
  }
}

extern "C" void kernel_launch(void* const* d_in, const int* in_sizes, int n_in,
                              void* d_out, int out_size, void* d_ws, size_t ws_size,
                              hipStream_t stream) {
  const float* query = (const float*)d_in[0];
  const float* key   = (const float*)d_in[1];
  const float* value = (const float*)d_in[2];
  const float* Wq    = (const float*)d_in[3];
  const float* bq    = (const float*)d_in[4];
  const float* Wk    = (const float*)d_in[5];
  const float* bk    = (const float*)d_in[6];
  const float* Wv    = (const float*)d_in[7];
  const float* bv    = (const float*)d_in[8];

  float* out   = (float*)d_out;
  float* probs = out + (size_t)SEQ * BATCH * DM;        // BATCH*SEQ*SEQ floats

  unsigned short* WvT  = (unsigned short*)d_ws;
  unsigned short* WqkT = WvT  + (size_t)DM * DM;
  unsigned short* qbf  = WqkT + (size_t)2 * DI * DM;
  unsigned short* kbf  = qbf  + (size_t)BATCH * SEQ * DI;
  unsigned short* vT   = kbf  + (size_t)BATCH * SEQ * DI;
  unsigned short* smb  = vT   + (size_t)BATCH * DM * SEQ;
  float* colsum = (float*)(smb + (size_t)BATCH * SEQ * SEQ);
  float* invcol = colsum + (size_t)BATCH * SEQ;

  wqkt_kernel<<<dim3(16, 2), 256, 0, stream>>>(Wq, Wk, WqkT);
  qkproj_mfma<<<dim3(SEQ * BATCH / 256, 2), 256, 0, stream>>>(
      query, key, WqkT, bq, bk, qbf, kbf);
  wvt_kernel<<<dim3(16, 16), 256, 0, stream>>>(Wv, WvT);
  vproj_mfma<<<dim3(SEQ * BATCH / 128, DM / 128), 256, 0, stream>>>(value, WvT, bv, vT);
  scores_mfma<<<dim3(SEQ / 128, SEQ / 128, BATCH), 256, 0, stream>>>(qbf, kbf, probs);
  softmax_kernel<<<dim3(SEQ, BATCH), 256, 0, stream>>>(probs);
  zero_kernel<<<(BATCH * SEQ + 255) / 256, 256, 0, stream>>>(colsum, BATCH * SEQ);
  colsum_kernel<<<dim3(SEQ / 256, SEQ / 128, BATCH), 256, 0, stream>>>(probs, colsum);
  invcol_kernel<<<(BATCH * SEQ + 255) / 256, 256, 0, stream>>>(colsum, invcol, BATCH * SEQ);
  renorm_kernel<<<(BATCH * SEQ * SEQ / 4) / 256, 256, 0, stream>>>(probs, invcol, smb);
  aten_mfma<<<dim3(SEQ / 128, DM / 128, BATCH), 256, 0, stream>>>(smb, vT, out);
}